// Round 5
// baseline (388.119 us; speedup 1.0000x reference)
//
#include <hip/hip_runtime.h>
#include <math.h>

#define B_ 128
#define D_ 128
#define Q_ 256
#define L_ 1024

typedef __attribute__((ext_vector_type(8))) short s16x8;
typedef __attribute__((ext_vector_type(4))) float f32x4;
typedef unsigned short u16;

__device__ __forceinline__ u16 f2bf(float x) {
  unsigned u = __float_as_uint(x);
  u += 0x7FFF + ((u >> 16) & 1);  // round-to-nearest-even
  return (u16)(u >> 16);
}
__device__ __forceinline__ float bf2f(u16 h) {
  return __uint_as_float(((unsigned)h) << 16);
}
__device__ __forceinline__ uint2 pack4bf(float4 v) {
  uint2 r;
  r.x = ((unsigned)f2bf(v.y) << 16) | (unsigned)f2bf(v.x);
  r.y = ((unsigned)f2bf(v.w) << 16) | (unsigned)f2bf(v.z);
  return r;
}
__device__ __forceinline__ void split8(const float* x, s16x8& hi, s16x8& lo) {
#pragma unroll
  for (int j = 0; j < 8; j++) {
    u16 h = f2bf(x[j]);
    hi[j] = (short)h;
    lo[j] = (short)f2bf(x[j] - bf2f(h));
  }
}

// ---------------------------------------------------------------------------
// kA = k1_stats v2: OCCUPANCY RESTRUCTURE. R0-R4 established k1 is pinned
// ~85-93us regardless of load path (R1), store path (R2), or store volume
// (R4) -> latency-bound at ~2 waves/SIMD (acc[4][4]=64 regs + ~100 arch
// VGPR = ~164/wave). v2: 512 thr / 8 waves, each wave 32 q -> acc[2][4]=32
// regs; one B-fragment live at a time; __launch_bounds__(512,4) caps VGPR
// at 128 -> 4 waves/SIMD, 2 blocks/CU (50% occ, was ~25%). B-side split
// work duplicated across 8 waves (L2-hit reloads) — acceptable, VALU had
// slack (R1: 23% busy at same 93us).
// Outputs: fm/fs softmax1 stats per l (1MB), pd partial denominators (2MB).
// Block = full Q (256q) x 64l; grid (L/64=16, B).
// ---------------------------------------------------------------------------
__global__ __launch_bounds__(512, 4) void k1_stats(
    const float* __restrict__ query, const float* __restrict__ ctx,
    float* __restrict__ pd, float* __restrict__ fmg, float* __restrict__ fsg) {
  __shared__ float sm[8][64], ss[8][64], fm[64], fs[64];
  const int lt = blockIdx.x, b = blockIdx.y;
  const int l0 = lt * 64;
  const int tid = threadIdx.x;
  const int wq = tid >> 6;  // wave = 32-q strip (0..7)
  const int lane = tid & 63, quad = lane >> 4, l15 = lane & 15;

  const float* Qb = query + (size_t)b * D_ * Q_;
  const float* Cb = ctx + (size_t)b * D_ * L_ + l0;

  f32x4 acc[2][4];
#pragma unroll
  for (int mi = 0; mi < 2; mi++)
#pragma unroll
    for (int ni = 0; ni < 4; ni++) acc[mi][ni] = (f32x4){0.f, 0.f, 0.f, 0.f};

#pragma unroll 2
  for (int k0 = 0; k0 < D_; k0 += 32) {
    const int kq = k0 + quad * 8;  // this lane's 8 k rows
    s16x8 ah[2], al[2];
#pragma unroll
    for (int mi = 0; mi < 2; mi++) {
      const float* p = Qb + (size_t)kq * Q_ + wq * 32 + mi * 16 + l15;
      float x[8];
#pragma unroll
      for (int j = 0; j < 8; j++) x[j] = p[(size_t)j * Q_];
      split8(x, ah[mi], al[mi]);
    }
#pragma unroll
    for (int ni = 0; ni < 4; ni++) {
      const float* p = Cb + (size_t)kq * L_ + ni * 16 + l15;
      float x[8];
#pragma unroll
      for (int j = 0; j < 8; j++) x[j] = p[(size_t)j * L_];
      s16x8 bh, bl;
      split8(x, bh, bl);
#pragma unroll
      for (int mi = 0; mi < 2; mi++) {
        acc[mi][ni] = __builtin_amdgcn_mfma_f32_16x16x32_bf16(
            ah[mi], bh, acc[mi][ni], 0, 0, 0);
        acc[mi][ni] = __builtin_amdgcn_mfma_f32_16x16x32_bf16(
            ah[mi], bl, acc[mi][ni], 0, 0, 0);
        acc[mi][ni] = __builtin_amdgcn_mfma_f32_16x16x32_bf16(
            al[mi], bh, acc[mi][ni], 0, 0, 0);
      }
    }
  }

  // ---- first softmax stats (over q): per-wave over its 32 q, per l col
#pragma unroll
  for (int ni = 0; ni < 4; ni++) {
    float m = -1e30f;
#pragma unroll
    for (int mi = 0; mi < 2; mi++)
#pragma unroll
      for (int r = 0; r < 4; r++) m = fmaxf(m, acc[mi][ni][r]);
    m = fmaxf(m, __shfl_xor(m, 16));
    m = fmaxf(m, __shfl_xor(m, 32));
    float s = 0.f;
#pragma unroll
    for (int mi = 0; mi < 2; mi++)
#pragma unroll
      for (int r = 0; r < 4; r++) s += __expf(acc[mi][ni][r] - m);
    s += __shfl_xor(s, 16);
    s += __shfl_xor(s, 32);
    if (quad == 0) {
      sm[wq][ni * 16 + l15] = m;
      ss[wq][ni * 16 + l15] = s;
    }
  }
  __syncthreads();
  if (tid < 64) {
    float M = -1e30f;
#pragma unroll
    for (int t = 0; t < 8; t++) M = fmaxf(M, sm[t][tid]);
    float S = 0.f;
#pragma unroll
    for (int t = 0; t < 8; t++) S += ss[t][tid] * __expf(sm[t][tid] - M);
    const float iS = 1.f / S;
    fm[tid] = M;
    fs[tid] = iS;
    fmg[(size_t)b * L_ + l0 + tid] = M;
    fsg[(size_t)b * L_ + l0 + tid] = iS;
  }
  __syncthreads();

  float fmv[4], fiv[4];
#pragma unroll
  for (int ni = 0; ni < 4; ni++) {
    fmv[ni] = fm[ni * 16 + l15];
    fiv[ni] = fs[ni * 16 + l15];
  }
  float dsum[2][4];
#pragma unroll
  for (int mi = 0; mi < 2; mi++)
#pragma unroll
    for (int r = 0; r < 4; r++) dsum[mi][r] = 0.f;
#pragma unroll
  for (int mi = 0; mi < 2; mi++)
#pragma unroll
    for (int r = 0; r < 4; r++) {
#pragma unroll
      for (int ni = 0; ni < 4; ni++) {
        float a = __expf(acc[mi][ni][r] - fmv[ni]) * fiv[ni];
        dsum[mi][r] += __expf(4.f * a);
      }
    }
#pragma unroll
  for (int mi = 0; mi < 2; mi++)
#pragma unroll
    for (int r = 0; r < 4; r++) {
      float v = dsum[mi][r];
      v += __shfl_xor(v, 1);
      v += __shfl_xor(v, 2);
      v += __shfl_xor(v, 4);
      v += __shfl_xor(v, 8);
      dsum[mi][r] = v;
    }
  if (l15 == 0) {
#pragma unroll
    for (int mi = 0; mi < 2; mi++)
#pragma unroll
      for (int r = 0; r < 4; r++)
        pd[(size_t)lt * (B_ * Q_) + b * Q_ + wq * 32 + mi * 16 + quad * 4 +
           r] = dsum[mi][r];
  }
}

// ---------------------------------------------------------------------------
// kB = k3_fused v2: OCCUPANCY RESTRUCTURE. q-tile 64 -> 32: LDS 62.7KB ->
// 38.8KB => 4 blocks/CU (was 2). grid (Q/32=8, B) = 1024 blocks. Per-wave
// output: 32d x 32q (accw[2][2]); score waves each own 16 l x 32 q.
// Same math as R4's proven k3 (S^T recompute, softmax1 from fm/fs,
// softmax2 from pd-derived invd, fp32 map scatter, weighted GEMM from
// As/Bs LDS). ctx staging + score reads get 2x L2-hit redundancy (cheap).
// ---------------------------------------------------------------------------
__global__ __launch_bounds__(256, 4) void k3_fused(
    const float* __restrict__ query, const float* __restrict__ ctx,
    const float* __restrict__ pd, const float* __restrict__ fmg,
    const float* __restrict__ fsg, float* __restrict__ attn,
    float* __restrict__ W) {
  __shared__ u16 QsH[32][132], QsL[32][132];  // query^T [q][d=128+pad]
  __shared__ u16 As[128][68];                 // ctx [d][l-tile 64+pad] hi
  __shared__ u16 Bs[32][68];                  // attn_c bf16 [q][l-tile]
  __shared__ float ivs[32];
  const int b = blockIdx.y, q0 = blockIdx.x * 32;
  const int tid = threadIdx.x;
  const int w = tid >> 6, lane = tid & 63, quad = lane >> 4, l15 = lane & 15;

  // ---- folded k2: invd for this block's 32 q (same t-order as old k2)
  if (tid < 32) {
    float s = 0.f;
#pragma unroll
    for (int t = 0; t < 16; t++)
      s += pd[(size_t)t * (B_ * Q_) + b * Q_ + q0 + tid];
    ivs[tid] = 1.f / s;
  }
  // ---- stage query^T tile once: [32q][128d] hi/lo (coalesced fp32 reads)
  {
    const int dr = tid >> 1;        // 0..127
    const int qc = (tid & 1) * 16;  // 0 / 16
    const float* qp = query + ((size_t)b * D_ + dr) * Q_ + q0 + qc;
#pragma unroll
    for (int c = 0; c < 4; c++) {
      float4 v = *(const float4*)(qp + c * 4);
      float xs[4] = {v.x, v.y, v.z, v.w};
#pragma unroll
      for (int j = 0; j < 4; j++) {
        u16 h = f2bf(xs[j]);
        QsH[qc + c * 4 + j][dr] = h;
        QsL[qc + c * 4 + j][dr] = f2bf(xs[j] - bf2f(h));
      }
    }
  }
  __syncthreads();

  float ivq[2];
#pragma unroll
  for (int ni = 0; ni < 2; ni++) ivq[ni] = ivs[ni * 16 + l15];
  const int wd = w * 32;
  f32x4 accw[2][2];
#pragma unroll
  for (int mi = 0; mi < 2; mi++)
#pragma unroll
    for (int ni = 0; ni < 2; ni++) accw[mi][ni] = (f32x4){0.f, 0.f, 0.f, 0.f};

  const float* Cb = ctx + (size_t)b * D_ * L_;
  float* Mapb = attn + ((size_t)b * Q_ + q0) * L_;
  const float* fmb = fmg + (size_t)b * L_;
  const float* fsb = fsg + (size_t)b * L_;
  const int dd = tid >> 3;        // 0..31 (As staging row)
  const int lc8 = (tid & 7) * 8;  // 0..56 (As staging col)

  for (int l0 = 0; l0 < L_; l0 += 64) {
    if (l0) __syncthreads();  // protect As/Bs overwrite vs prev readers
    // ---- stage As: ctx[128d][64l] hi, coalesced reads, [d][l] layout
#pragma unroll
    for (int h = 0; h < 4; h++) {
      const int d = dd + h * 32;
      const float* cp = Cb + (size_t)d * L_ + l0 + lc8;
      float4 v0 = *(const float4*)cp;
      float4 v1 = *(const float4*)(cp + 4);
      *(uint2*)&As[d][lc8] = pack4bf(v0);
      *(uint2*)&As[d][lc8 + 4] = pack4bf(v1);
    }

    // ---- score phase: S^T rows l = l0+16w+(quad*4+r), cols q = q0+ni*16+l15
    f32x4 accs[2];
#pragma unroll
    for (int ni = 0; ni < 2; ni++) accs[ni] = (f32x4){0.f, 0.f, 0.f, 0.f};
#pragma unroll
    for (int ks = 0; ks < 4; ks++) {
      const float* ap =
          Cb + (size_t)(ks * 32 + quad * 8) * L_ + l0 + 16 * w + l15;
      float x[8];
#pragma unroll
      for (int j = 0; j < 8; j++) x[j] = ap[(size_t)j * L_];
      s16x8 ch, cl;
      split8(x, ch, cl);
#pragma unroll
      for (int ni = 0; ni < 2; ni++) {
        const s16x8 qh = *(const s16x8*)&QsH[ni * 16 + l15][ks * 32 + quad * 8];
        const s16x8 ql = *(const s16x8*)&QsL[ni * 16 + l15][ks * 32 + quad * 8];
        accs[ni] =
            __builtin_amdgcn_mfma_f32_16x16x32_bf16(ch, qh, accs[ni], 0, 0, 0);
        accs[ni] =
            __builtin_amdgcn_mfma_f32_16x16x32_bf16(ch, ql, accs[ni], 0, 0, 0);
        accs[ni] =
            __builtin_amdgcn_mfma_f32_16x16x32_bf16(cl, qh, accs[ni], 0, 0, 0);
      }
    }

    // ---- softmax1 (stats) + softmax2 (invd): map scatter + Bs bf16 tile
    float fml[4], fsl[4];
#pragma unroll
    for (int r = 0; r < 4; r++) {
      fml[r] = fmb[l0 + 16 * w + quad * 4 + r];
      fsl[r] = fsb[l0 + 16 * w + quad * 4 + r];
    }
#pragma unroll
    for (int ni = 0; ni < 2; ni++)
#pragma unroll
      for (int r = 0; r < 4; r++) {
        float a = __expf(accs[ni][r] - fml[r]) * fsl[r];
        float t = __expf(4.f * a) * ivq[ni];
        Mapb[(size_t)(ni * 16 + l15) * L_ + l0 + 16 * w + quad * 4 + r] = t;
        Bs[ni * 16 + l15][16 * w + quad * 4 + r] = f2bf(t);
      }
    __syncthreads();

    // ---- weighted GEMM: accw += ctx[d][l] * attn_c[q][l]
#pragma unroll
    for (int ks2 = 0; ks2 < 2; ks2++) {
      s16x8 af[2], bq[2];
#pragma unroll
      for (int mi = 0; mi < 2; mi++)
        af[mi] = *(const s16x8*)&As[wd + mi * 16 + l15][ks2 * 32 + quad * 8];
#pragma unroll
      for (int ni = 0; ni < 2; ni++)
        bq[ni] = *(const s16x8*)&Bs[ni * 16 + l15][ks2 * 32 + quad * 8];
#pragma unroll
      for (int mi = 0; mi < 2; mi++)
#pragma unroll
        for (int ni = 0; ni < 2; ni++)
          accw[mi][ni] = __builtin_amdgcn_mfma_f32_16x16x32_bf16(
              af[mi], bq[ni], accw[mi][ni], 0, 0, 0);
    }
  }

  float* Wb = W + (size_t)b * D_ * Q_;
#pragma unroll
  for (int mi = 0; mi < 2; mi++)
#pragma unroll
    for (int ni = 0; ni < 2; ni++)
#pragma unroll
      for (int r = 0; r < 4; r++)
        Wb[(size_t)(wd + mi * 16 + quad * 4 + r) * Q_ + q0 + ni * 16 + l15] =
            accw[mi][ni][r];
}

// ---------------------------------------------------------------------------
// Legacy trio (R0, verbatim) — fallback only if workspace is too small.
// ---------------------------------------------------------------------------
__global__ __launch_bounds__(256, 2) void k1_attnq_legacy(
    const float* __restrict__ query, const float* __restrict__ ctx,
    float* __restrict__ attq, float* __restrict__ pd) {
  __shared__ float sm[4][64], ss[4][64], fm[64], fs[64];
  const int lt = blockIdx.x, b = blockIdx.y;
  const int l0 = lt * 64;
  const int tid = threadIdx.x;
  const int wq = tid >> 6;
  const int lane = tid & 63, quad = lane >> 4, l15 = lane & 15;

  const float* Qb = query + (size_t)b * D_ * Q_;
  const float* Cb = ctx + (size_t)b * D_ * L_ + l0;

  f32x4 acc[4][4];
#pragma unroll
  for (int mi = 0; mi < 4; mi++)
#pragma unroll
    for (int ni = 0; ni < 4; ni++) acc[mi][ni] = (f32x4){0.f, 0.f, 0.f, 0.f};

#pragma unroll 2
  for (int k0 = 0; k0 < D_; k0 += 32) {
    const int kq = k0 + quad * 8;
    s16x8 ah[4], al[4], bh[4], bl[4];
#pragma unroll
    for (int mi = 0; mi < 4; mi++) {
      const float* p = Qb + (size_t)kq * Q_ + wq * 64 + mi * 16 + l15;
      float x[8];
#pragma unroll
      for (int j = 0; j < 8; j++) x[j] = p[(size_t)j * Q_];
      split8(x, ah[mi], al[mi]);
    }
#pragma unroll
    for (int ni = 0; ni < 4; ni++) {
      const float* p = Cb + (size_t)kq * L_ + ni * 16 + l15;
      float x[8];
#pragma unroll
      for (int j = 0; j < 8; j++) x[j] = p[(size_t)j * L_];
      split8(x, bh[ni], bl[ni]);
    }
#pragma unroll
    for (int mi = 0; mi < 4; mi++)
#pragma unroll
      for (int ni = 0; ni < 4; ni++) {
        acc[mi][ni] = __builtin_amdgcn_mfma_f32_16x16x32_bf16(
            ah[mi], bh[ni], acc[mi][ni], 0, 0, 0);
        acc[mi][ni] = __builtin_amdgcn_mfma_f32_16x16x32_bf16(
            ah[mi], bl[ni], acc[mi][ni], 0, 0, 0);
        acc[mi][ni] = __builtin_amdgcn_mfma_f32_16x16x32_bf16(
            al[mi], bh[ni], acc[mi][ni], 0, 0, 0);
      }
  }

#pragma unroll
  for (int ni = 0; ni < 4; ni++) {
    float m = -1e30f;
#pragma unroll
    for (int mi = 0; mi < 4; mi++)
#pragma unroll
      for (int r = 0; r < 4; r++) m = fmaxf(m, acc[mi][ni][r]);
    m = fmaxf(m, __shfl_xor(m, 16));
    m = fmaxf(m, __shfl_xor(m, 32));
    float s = 0.f;
#pragma unroll
    for (int mi = 0; mi < 4; mi++)
#pragma unroll
      for (int r = 0; r < 4; r++) s += __expf(acc[mi][ni][r] - m);
    s += __shfl_xor(s, 16);
    s += __shfl_xor(s, 32);
    if (quad == 0) {
      sm[wq][ni * 16 + l15] = m;
      ss[wq][ni * 16 + l15] = s;
    }
  }
  __syncthreads();
  if (tid < 64) {
    float m0 = sm[0][tid], m1 = sm[1][tid], m2 = sm[2][tid], m3 = sm[3][tid];
    float M = fmaxf(fmaxf(m0, m1), fmaxf(m2, m3));
    float S = ss[0][tid] * __expf(m0 - M) + ss[1][tid] * __expf(m1 - M) +
              ss[2][tid] * __expf(m2 - M) + ss[3][tid] * __expf(m3 - M);
    fm[tid] = M;
    fs[tid] = 1.f / S;
  }
  __syncthreads();

  float fmv[4], fiv[4];
#pragma unroll
  for (int ni = 0; ni < 4; ni++) {
    fmv[ni] = fm[ni * 16 + l15];
    fiv[ni] = fs[ni * 16 + l15];
  }
  float* Ab = attq + ((size_t)b * Q_ + wq * 64) * L_ + l0;
  float dsum[4][4];
#pragma unroll
  for (int mi = 0; mi < 4; mi++)
#pragma unroll
    for (int r = 0; r < 4; r++) dsum[mi][r] = 0.f;
#pragma unroll
  for (int mi = 0; mi < 4; mi++)
#pragma unroll
    for (int r = 0; r < 4; r++) {
      const int q = mi * 16 + quad * 4 + r;
#pragma unroll
      for (int ni = 0; ni < 4; ni++) {
        float a = __expf(acc[mi][ni][r] - fmv[ni]) * fiv[ni];
        Ab[(size_t)q * L_ + ni * 16 + l15] = a;
        dsum[mi][r] += __expf(4.f * a);
      }
    }
#pragma unroll
  for (int mi = 0; mi < 4; mi++)
#pragma unroll
    for (int r = 0; r < 4; r++) {
      float v = dsum[mi][r];
      v += __shfl_xor(v, 1);
      v += __shfl_xor(v, 2);
      v += __shfl_xor(v, 4);
      v += __shfl_xor(v, 8);
      dsum[mi][r] = v;
    }
  if (l15 == 0) {
#pragma unroll
    for (int mi = 0; mi < 4; mi++)
#pragma unroll
      for (int r = 0; r < 4; r++)
        pd[(size_t)lt * (B_ * Q_) + b * Q_ + wq * 64 + mi * 16 + quad * 4 +
           r] = dsum[mi][r];
  }
}

__global__ __launch_bounds__(256) void k2_invd(const float* __restrict__ pd,
                                               float* __restrict__ invd) {
  const int i = blockIdx.x * 256 + threadIdx.x;
  float s = 0.f;
#pragma unroll
  for (int t = 0; t < 16; t++) s += pd[(size_t)t * (B_ * Q_) + i];
  invd[i] = 1.f / s;
}

__global__ __launch_bounds__(256) void k4_weighted(
    const float* __restrict__ ctx, float* __restrict__ attn,
    const float* __restrict__ invd, float* __restrict__ W) {
  __shared__ unsigned short As[128][32];
  __shared__ unsigned short Bs[64][32];
  const int b = blockIdx.y, q0 = blockIdx.x * 64;
  const int tid = threadIdx.x;
  const int w = tid >> 6, lane = tid & 63, quad = lane >> 4, l15 = lane & 15;
  const int wd = (w >> 1) * 64, wn = (w & 1) * 32;

  const float* Cb = ctx + (size_t)b * D_ * L_;
  float* Ab = attn + ((size_t)b * Q_ + q0) * L_;

  const int lc = (tid & 7) * 4;
  const int rr = tid >> 3;
  const float id0 = invd[b * Q_ + q0 + rr];
  const float id1 = invd[b * Q_ + q0 + rr + 32];

  f32x4 acc[4][2];
#pragma unroll
  for (int mi = 0; mi < 4; mi++)
#pragma unroll
    for (int ni = 0; ni < 2; ni++) acc[mi][ni] = (f32x4){0.f, 0.f, 0.f, 0.f};

  for (int l0 = 0; l0 < L_; l0 += 32) {
    if (l0) __syncthreads();
#pragma unroll
    for (int h = 0; h < 4; h++) {
      const int d = rr + h * 32;
      float4 cv = *(const float4*)(Cb + (size_t)d * L_ + l0 + lc);
      *(uint2*)&As[d][lc] = pack4bf(cv);
    }
#pragma unroll
    for (int h = 0; h < 2; h++) {
      const int q = rr + h * 32;
      float* p = Ab + (size_t)q * L_ + l0 + lc;
      float4 a = *(const float4*)p;
      const float idv = h ? id1 : id0;
      float4 t;
      t.x = __expf(4.f * a.x) * idv;
      t.y = __expf(4.f * a.y) * idv;
      t.z = __expf(4.f * a.z) * idv;
      t.w = __expf(4.f * a.w) * idv;
      *(float4*)p = t;
      *(uint2*)&Bs[q][lc] = pack4bf(t);
    }
    __syncthreads();

    s16x8 af[4], bq[2];
#pragma unroll
    for (int mi = 0; mi < 4; mi++)
      af[mi] = *(const s16x8*)&As[wd + mi * 16 + l15][quad * 8];
#pragma unroll
    for (int ni = 0; ni < 2; ni++)
      bq[ni] = *(const s16x8*)&Bs[wn + ni * 16 + l15][quad * 8];
#pragma unroll
    for (int mi = 0; mi < 4; mi++)
#pragma unroll
      for (int ni = 0; ni < 2; ni++)
        acc[mi][ni] = __builtin_amdgcn_mfma_f32_16x16x32_bf16(
            af[mi], bq[ni], acc[mi][ni], 0, 0, 0);
  }

  float* Wb = W + (size_t)b * D_ * Q_;
#pragma unroll
  for (int mi = 0; mi < 4; mi++)
#pragma unroll
    for (int ni = 0; ni < 2; ni++)
#pragma unroll
      for (int r = 0; r < 4; r++)
        Wb[(size_t)(wd + mi * 16 + quad * 4 + r) * Q_ + q0 + wn + ni * 16 +
           l15] = acc[mi][ni][r];
}

// ---------------------------------------------------------------------------
// d_out: [W (B*D*Q) | map (B*Q*L)]. Main path: k1_stats (512thr, 50% occ)
// writes stats only -> k3_fused (32-q tiles, 4 blocks/CU) recomputes scores,
// writes map + W. attn_q never materialized. Fallback: legacy trio.
// ---------------------------------------------------------------------------
extern "C" void kernel_launch(void* const* d_in, const int* in_sizes, int n_in,
                              void* d_out, int out_size, void* d_ws,
                              size_t ws_size, hipStream_t stream) {
  (void)in_sizes;
  (void)n_in;
  (void)out_size;
  const float* query = (const float*)d_in[0];
  const float* ctx = (const float*)d_in[1];
  float* W = (float*)d_out;
  float* attn = (float*)d_out + (size_t)B_ * D_ * Q_;

  const size_t need =
      ((size_t)16 * B_ * Q_ + (size_t)2 * B_ * L_) * sizeof(float);
  if (d_ws && ws_size >= need) {
    float* pd = (float*)d_ws;
    float* fm = pd + (size_t)16 * B_ * Q_;
    float* fs = fm + (size_t)B_ * L_;
    k1_stats<<<dim3(L_ / 64, B_), 512, 0, stream>>>(query, ctx, pd, fm, fs);
    k3_fused<<<dim3(Q_ / 32, B_), 256, 0, stream>>>(query, ctx, pd, fm, fs,
                                                    attn, W);
  } else {
    const size_t need_pd = (size_t)17 * B_ * Q_ * sizeof(float);
    float* pd = (d_ws && ws_size >= need_pd) ? (float*)d_ws : W;
    float* invd = pd + (size_t)16 * B_ * Q_;
    k1_attnq_legacy<<<dim3(L_ / 64, B_), 256, 0, stream>>>(query, ctx, attn,
                                                           pd);
    k2_invd<<<dim3(B_ * Q_ / 256), 256, 0, stream>>>(pd, invd);
    k4_weighted<<<dim3(Q_ / 64, B_), 256, 0, stream>>>(ctx, attn, invd, W);
  }
}

// Round 6
// 288.073 us; speedup vs baseline: 1.3473x; 1.3473x over previous
//
#include <hip/hip_runtime.h>
#include <math.h>

#define B_ 128
#define D_ 128
#define Q_ 256
#define L_ 1024

typedef __attribute__((ext_vector_type(8))) short s16x8;
typedef __attribute__((ext_vector_type(4))) float f32x4;
typedef unsigned short u16;

__device__ __forceinline__ u16 f2bf(float x) {
  unsigned u = __float_as_uint(x);
  u += 0x7FFF + ((u >> 16) & 1);  // round-to-nearest-even
  return (u16)(u >> 16);
}
__device__ __forceinline__ float bf2f(u16 h) {
  return __uint_as_float(((unsigned)h) << 16);
}
__device__ __forceinline__ uint2 pack4bf(float4 v) {
  uint2 r;
  r.x = ((unsigned)f2bf(v.y) << 16) | (unsigned)f2bf(v.x);
  r.y = ((unsigned)f2bf(v.w) << 16) | (unsigned)f2bf(v.z);
  return r;
}
__device__ __forceinline__ void split8(const float* x, s16x8& hi, s16x8& lo) {
#pragma unroll
  for (int j = 0; j < 8; j++) {
    u16 h = f2bf(x[j]);
    hi[j] = (short)h;
    lo[j] = (short)f2bf(x[j] - bf2f(h));
  }
}

// ---------------------------------------------------------------------------
// kA = k1_stats: EXACT R4 body (best measured ~85us). R5's occupancy variant
// (+50% issue work) ran ~126us -> k1 tracks issued work, occupancy theory
// dead; this structure is the floor for now.
// ROUND-6: 1-D grid + XCD-locality swizzle. All 16 l-tile blocks of one b
// land on one XCD (p%8 = b%8) so the shared 128KB query panel stays in that
// XCD's L2. Bijective decode: b=(p&7)+8*(s>>4), lt=s&15, s=p>>3.
// Outputs: fm/fs softmax1 stats per l (1MB), pd partials (2MB). 4 waves.
// ---------------------------------------------------------------------------
__global__ __launch_bounds__(256, 2) void k1_stats(
    const float* __restrict__ query, const float* __restrict__ ctx,
    float* __restrict__ pd, float* __restrict__ fmg, float* __restrict__ fsg) {
  __shared__ float sm[4][64], ss[4][64], fm[64], fs[64];
  const int p = blockIdx.x;
  const int xcd = p & 7, s = p >> 3;
  const int b = xcd + 8 * (s >> 4);  // 16 b-groups per XCD
  const int lt = s & 15;
  const int l0 = lt * 64;
  const int tid = threadIdx.x;
  const int wq = tid >> 6;  // wave = q-strip (0..3)
  const int lane = tid & 63, quad = lane >> 4, l15 = lane & 15;

  const float* Qb = query + (size_t)b * D_ * Q_;
  const float* Cb = ctx + (size_t)b * D_ * L_ + l0;

  f32x4 acc[4][4];
#pragma unroll
  for (int mi = 0; mi < 4; mi++)
#pragma unroll
    for (int ni = 0; ni < 4; ni++) acc[mi][ni] = (f32x4){0.f, 0.f, 0.f, 0.f};

#pragma unroll 2
  for (int k0 = 0; k0 < D_; k0 += 32) {
    const int kq = k0 + quad * 8;  // this lane's 8 k rows
    s16x8 ah[4], al[4], bh[4], bl[4];
#pragma unroll
    for (int mi = 0; mi < 4; mi++) {
      const float* p2 = Qb + (size_t)kq * Q_ + wq * 64 + mi * 16 + l15;
      float x[8];
#pragma unroll
      for (int j = 0; j < 8; j++) x[j] = p2[(size_t)j * Q_];
      split8(x, ah[mi], al[mi]);
    }
#pragma unroll
    for (int ni = 0; ni < 4; ni++) {
      const float* p2 = Cb + (size_t)kq * L_ + ni * 16 + l15;
      float x[8];
#pragma unroll
      for (int j = 0; j < 8; j++) x[j] = p2[(size_t)j * L_];
      split8(x, bh[ni], bl[ni]);
    }
#pragma unroll
    for (int mi = 0; mi < 4; mi++)
#pragma unroll
      for (int ni = 0; ni < 4; ni++) {
        acc[mi][ni] = __builtin_amdgcn_mfma_f32_16x16x32_bf16(
            ah[mi], bh[ni], acc[mi][ni], 0, 0, 0);
        acc[mi][ni] = __builtin_amdgcn_mfma_f32_16x16x32_bf16(
            ah[mi], bl[ni], acc[mi][ni], 0, 0, 0);
        acc[mi][ni] = __builtin_amdgcn_mfma_f32_16x16x32_bf16(
            al[mi], bh[ni], acc[mi][ni], 0, 0, 0);
      }
  }

  // ---- first softmax stats (over q), final in-block (block covers 256 q)
#pragma unroll
  for (int ni = 0; ni < 4; ni++) {
    float m = -1e30f;
#pragma unroll
    for (int mi = 0; mi < 4; mi++)
#pragma unroll
      for (int r = 0; r < 4; r++) m = fmaxf(m, acc[mi][ni][r]);
    m = fmaxf(m, __shfl_xor(m, 16));
    m = fmaxf(m, __shfl_xor(m, 32));
    float sv = 0.f;
#pragma unroll
    for (int mi = 0; mi < 4; mi++)
#pragma unroll
      for (int r = 0; r < 4; r++) sv += __expf(acc[mi][ni][r] - m);
    sv += __shfl_xor(sv, 16);
    sv += __shfl_xor(sv, 32);
    if (quad == 0) {
      sm[wq][ni * 16 + l15] = m;
      ss[wq][ni * 16 + l15] = sv;
    }
  }
  __syncthreads();
  if (tid < 64) {
    float m0 = sm[0][tid], m1 = sm[1][tid], m2 = sm[2][tid], m3 = sm[3][tid];
    float M = fmaxf(fmaxf(m0, m1), fmaxf(m2, m3));
    float S = ss[0][tid] * __expf(m0 - M) + ss[1][tid] * __expf(m1 - M) +
              ss[2][tid] * __expf(m2 - M) + ss[3][tid] * __expf(m3 - M);
    fm[tid] = M;
    fs[tid] = 1.f / S;
    fmg[(size_t)b * L_ + l0 + tid] = M;
    fsg[(size_t)b * L_ + l0 + tid] = 1.f / S;
  }
  __syncthreads();

  float fmv[4], fiv[4];
#pragma unroll
  for (int ni = 0; ni < 4; ni++) {
    fmv[ni] = fm[ni * 16 + l15];
    fiv[ni] = fs[ni * 16 + l15];
  }
  float dsum[4][4];
#pragma unroll
  for (int mi = 0; mi < 4; mi++)
#pragma unroll
    for (int r = 0; r < 4; r++) dsum[mi][r] = 0.f;
#pragma unroll
  for (int mi = 0; mi < 4; mi++)
#pragma unroll
    for (int r = 0; r < 4; r++) {
#pragma unroll
      for (int ni = 0; ni < 4; ni++) {
        float a = __expf(acc[mi][ni][r] - fmv[ni]) * fiv[ni];
        dsum[mi][r] += __expf(4.f * a);
      }
    }
#pragma unroll
  for (int mi = 0; mi < 4; mi++)
#pragma unroll
    for (int r = 0; r < 4; r++) {
      float v = dsum[mi][r];
      v += __shfl_xor(v, 1);
      v += __shfl_xor(v, 2);
      v += __shfl_xor(v, 4);
      v += __shfl_xor(v, 8);
      dsum[mi][r] = v;
    }
  if (l15 == 0) {
#pragma unroll
    for (int mi = 0; mi < 4; mi++)
#pragma unroll
      for (int r = 0; r < 4; r++)
        pd[(size_t)lt * (B_ * Q_) + b * Q_ + wq * 64 + mi * 16 + quad * 4 +
           r] = dsum[mi][r];
  }
}

// ---------------------------------------------------------------------------
// kB = k3_fused: EXACT R4 body (64-q tiles, the version that passed at
// ~75-80us). R5's 32-q variant doubled ctx staging redundancy -> FETCH
// 328MB, 128us: k3 is traffic-bound, so ROUND-6 attacks exactly that:
// 1-D grid + XCD-locality swizzle. The 4 same-b blocks (which each stage
// the same 512KB ctx panel) now share one XCD (p%8 = b%8) -> panel is
// L2-resident (512KB << 4MB) for the re-reads, including the strided
// score-phase loads. Bijective decode: b=(p&7)+8*(s>>2), qt=s&3, s=p>>3.
// ---------------------------------------------------------------------------
__global__ __launch_bounds__(256, 2) void k3_fused(
    const float* __restrict__ query, const float* __restrict__ ctx,
    const float* __restrict__ pd, const float* __restrict__ fmg,
    const float* __restrict__ fsg, float* __restrict__ attn,
    float* __restrict__ W) {
  __shared__ u16 QsH[64][136], QsL[64][136];  // query^T [q][d=128+pad]
  __shared__ u16 As[128][72];                 // ctx [d][l-tile 64+pad] hi
  __shared__ u16 Bs[64][72];                  // attn_c bf16 [q][l-tile]
  __shared__ float ivs[64];
  const int p = blockIdx.x;
  const int xcd = p & 7, s = p >> 3;
  const int b = xcd + 8 * (s >> 2);  // 16 b-groups per XCD
  const int q0 = (s & 3) * 64;
  const int tid = threadIdx.x;
  const int w = tid >> 6, lane = tid & 63, quad = lane >> 4, l15 = lane & 15;

  // ---- folded k2: invd for this block's 64 q (same t-order as old k2)
  if (tid < 64) {
    float sv = 0.f;
#pragma unroll
    for (int t = 0; t < 16; t++)
      sv += pd[(size_t)t * (B_ * Q_) + b * Q_ + q0 + tid];
    ivs[tid] = 1.f / sv;
  }
  // ---- stage query^T tile once: [64q][128d] hi/lo (coalesced fp32 reads)
  {
    const int dr = tid >> 1;        // 0..127
    const int qc = (tid & 1) * 32;  // 0 / 32
    const float* qp = query + ((size_t)b * D_ + dr) * Q_ + q0 + qc;
#pragma unroll
    for (int c = 0; c < 8; c++) {
      float4 v = *(const float4*)(qp + c * 4);
      float xs[4] = {v.x, v.y, v.z, v.w};
#pragma unroll
      for (int j = 0; j < 4; j++) {
        u16 h = f2bf(xs[j]);
        QsH[qc + c * 4 + j][dr] = h;
        QsL[qc + c * 4 + j][dr] = f2bf(xs[j] - bf2f(h));
      }
    }
  }
  __syncthreads();

  float ivq[4];
#pragma unroll
  for (int ni = 0; ni < 4; ni++) ivq[ni] = ivs[ni * 16 + l15];
  const int wd = (w >> 1) * 64, wn = (w & 1) * 32;
  f32x4 accw[4][2];
#pragma unroll
  for (int mi = 0; mi < 4; mi++)
#pragma unroll
    for (int ni = 0; ni < 2; ni++) accw[mi][ni] = (f32x4){0.f, 0.f, 0.f, 0.f};

  const float* Cb = ctx + (size_t)b * D_ * L_;
  float* Mapb = attn + ((size_t)b * Q_ + q0) * L_;
  const float* fmb = fmg + (size_t)b * L_;
  const float* fsb = fsg + (size_t)b * L_;
  const int dd = tid >> 3;        // 0..31 (As staging row)
  const int lc8 = (tid & 7) * 8;  // 0..56 (As staging col)

  for (int l0 = 0; l0 < L_; l0 += 64) {
    if (l0) __syncthreads();  // protect As/Bs overwrite vs prev readers
    // ---- stage As: ctx[128d][64l] hi, coalesced reads, [d][l] layout
#pragma unroll
    for (int h = 0; h < 4; h++) {
      const int d = dd + h * 32;
      const float* cp = Cb + (size_t)d * L_ + l0 + lc8;
      float4 v0 = *(const float4*)cp;
      float4 v1 = *(const float4*)(cp + 4);
      *(uint2*)&As[d][lc8] = pack4bf(v0);
      *(uint2*)&As[d][lc8 + 4] = pack4bf(v1);
    }

    // ---- score phase: S^T rows l = l0+16w+l15, cols q = q0+ni*16+l15
    f32x4 accs[4];
#pragma unroll
    for (int ni = 0; ni < 4; ni++) accs[ni] = (f32x4){0.f, 0.f, 0.f, 0.f};
#pragma unroll
    for (int ks = 0; ks < 4; ks++) {
      const float* ap =
          Cb + (size_t)(ks * 32 + quad * 8) * L_ + l0 + 16 * w + l15;
      float x[8];
#pragma unroll
      for (int j = 0; j < 8; j++) x[j] = ap[(size_t)j * L_];
      s16x8 ch, cl;
      split8(x, ch, cl);
#pragma unroll
      for (int ni = 0; ni < 4; ni++) {
        const s16x8 qh = *(const s16x8*)&QsH[ni * 16 + l15][ks * 32 + quad * 8];
        const s16x8 ql = *(const s16x8*)&QsL[ni * 16 + l15][ks * 32 + quad * 8];
        accs[ni] =
            __builtin_amdgcn_mfma_f32_16x16x32_bf16(ch, qh, accs[ni], 0, 0, 0);
        accs[ni] =
            __builtin_amdgcn_mfma_f32_16x16x32_bf16(ch, ql, accs[ni], 0, 0, 0);
        accs[ni] =
            __builtin_amdgcn_mfma_f32_16x16x32_bf16(cl, qh, accs[ni], 0, 0, 0);
      }
    }

    // ---- softmax1 (stats) + softmax2 (invd): map scatter + Bs bf16 tile
    float fml[4], fsl[4];
#pragma unroll
    for (int r = 0; r < 4; r++) {
      fml[r] = fmb[l0 + 16 * w + quad * 4 + r];
      fsl[r] = fsb[l0 + 16 * w + quad * 4 + r];
    }
#pragma unroll
    for (int ni = 0; ni < 4; ni++)
#pragma unroll
      for (int r = 0; r < 4; r++) {
        float a = __expf(accs[ni][r] - fml[r]) * fsl[r];
        float t = __expf(4.f * a) * ivq[ni];
        Mapb[(size_t)(ni * 16 + l15) * L_ + l0 + 16 * w + quad * 4 + r] = t;
        Bs[ni * 16 + l15][16 * w + quad * 4 + r] = f2bf(t);
      }
    __syncthreads();

    // ---- weighted GEMM: accw += ctx[d][l] * attn_c[q][l]
#pragma unroll
    for (int ks2 = 0; ks2 < 2; ks2++) {
      s16x8 af[4], bq[2];
#pragma unroll
      for (int mi = 0; mi < 4; mi++)
        af[mi] = *(const s16x8*)&As[wd + mi * 16 + l15][ks2 * 32 + quad * 8];
#pragma unroll
      for (int ni = 0; ni < 2; ni++)
        bq[ni] = *(const s16x8*)&Bs[wn + ni * 16 + l15][ks2 * 32 + quad * 8];
#pragma unroll
      for (int mi = 0; mi < 4; mi++)
#pragma unroll
        for (int ni = 0; ni < 2; ni++)
          accw[mi][ni] = __builtin_amdgcn_mfma_f32_16x16x32_bf16(
              af[mi], bq[ni], accw[mi][ni], 0, 0, 0);
    }
  }

  float* Wb = W + (size_t)b * D_ * Q_;
#pragma unroll
  for (int mi = 0; mi < 4; mi++)
#pragma unroll
    for (int ni = 0; ni < 2; ni++)
#pragma unroll
      for (int r = 0; r < 4; r++)
        Wb[(size_t)(wd + mi * 16 + quad * 4 + r) * Q_ + q0 + wn + ni * 16 +
           l15] = accw[mi][ni][r];
}

// ---------------------------------------------------------------------------
// Legacy trio (R0, verbatim) — fallback only if workspace is too small.
// ---------------------------------------------------------------------------
__global__ __launch_bounds__(256, 2) void k1_attnq_legacy(
    const float* __restrict__ query, const float* __restrict__ ctx,
    float* __restrict__ attq, float* __restrict__ pd) {
  __shared__ float sm[4][64], ss[4][64], fm[64], fs[64];
  const int lt = blockIdx.x, b = blockIdx.y;
  const int l0 = lt * 64;
  const int tid = threadIdx.x;
  const int wq = tid >> 6;
  const int lane = tid & 63, quad = lane >> 4, l15 = lane & 15;

  const float* Qb = query + (size_t)b * D_ * Q_;
  const float* Cb = ctx + (size_t)b * D_ * L_ + l0;

  f32x4 acc[4][4];
#pragma unroll
  for (int mi = 0; mi < 4; mi++)
#pragma unroll
    for (int ni = 0; ni < 4; ni++) acc[mi][ni] = (f32x4){0.f, 0.f, 0.f, 0.f};

#pragma unroll 2
  for (int k0 = 0; k0 < D_; k0 += 32) {
    const int kq = k0 + quad * 8;
    s16x8 ah[4], al[4], bh[4], bl[4];
#pragma unroll
    for (int mi = 0; mi < 4; mi++) {
      const float* p = Qb + (size_t)kq * Q_ + wq * 64 + mi * 16 + l15;
      float x[8];
#pragma unroll
      for (int j = 0; j < 8; j++) x[j] = p[(size_t)j * Q_];
      split8(x, ah[mi], al[mi]);
    }
#pragma unroll
    for (int ni = 0; ni < 4; ni++) {
      const float* p = Cb + (size_t)kq * L_ + ni * 16 + l15;
      float x[8];
#pragma unroll
      for (int j = 0; j < 8; j++) x[j] = p[(size_t)j * L_];
      split8(x, bh[ni], bl[ni]);
    }
#pragma unroll
    for (int mi = 0; mi < 4; mi++)
#pragma unroll
      for (int ni = 0; ni < 4; ni++) {
        acc[mi][ni] = __builtin_amdgcn_mfma_f32_16x16x32_bf16(
            ah[mi], bh[ni], acc[mi][ni], 0, 0, 0);
        acc[mi][ni] = __builtin_amdgcn_mfma_f32_16x16x32_bf16(
            ah[mi], bl[ni], acc[mi][ni], 0, 0, 0);
        acc[mi][ni] = __builtin_amdgcn_mfma_f32_16x16x32_bf16(
            al[mi], bh[ni], acc[mi][ni], 0, 0, 0);
      }
  }

#pragma unroll
  for (int ni = 0; ni < 4; ni++) {
    float m = -1e30f;
#pragma unroll
    for (int mi = 0; mi < 4; mi++)
#pragma unroll
      for (int r = 0; r < 4; r++) m = fmaxf(m, acc[mi][ni][r]);
    m = fmaxf(m, __shfl_xor(m, 16));
    m = fmaxf(m, __shfl_xor(m, 32));
    float s = 0.f;
#pragma unroll
    for (int mi = 0; mi < 4; mi++)
#pragma unroll
      for (int r = 0; r < 4; r++) s += __expf(acc[mi][ni][r] - m);
    s += __shfl_xor(s, 16);
    s += __shfl_xor(s, 32);
    if (quad == 0) {
      sm[wq][ni * 16 + l15] = m;
      ss[wq][ni * 16 + l15] = s;
    }
  }
  __syncthreads();
  if (tid < 64) {
    float m0 = sm[0][tid], m1 = sm[1][tid], m2 = sm[2][tid], m3 = sm[3][tid];
    float M = fmaxf(fmaxf(m0, m1), fmaxf(m2, m3));
    float S = ss[0][tid] * __expf(m0 - M) + ss[1][tid] * __expf(m1 - M) +
              ss[2][tid] * __expf(m2 - M) + ss[3][tid] * __expf(m3 - M);
    fm[tid] = M;
    fs[tid] = 1.f / S;
  }
  __syncthreads();

  float fmv[4], fiv[4];
#pragma unroll
  for (int ni = 0; ni < 4; ni++) {
    fmv[ni] = fm[ni * 16 + l15];
    fiv[ni] = fs[ni * 16 + l15];
  }
  float* Ab = attq + ((size_t)b * Q_ + wq * 64) * L_ + l0;
  float dsum[4][4];
#pragma unroll
  for (int mi = 0; mi < 4; mi++)
#pragma unroll
    for (int r = 0; r < 4; r++) dsum[mi][r] = 0.f;
#pragma unroll
  for (int mi = 0; mi < 4; mi++)
#pragma unroll
    for (int r = 0; r < 4; r++) {
      const int q = mi * 16 + quad * 4 + r;
#pragma unroll
      for (int ni = 0; ni < 4; ni++) {
        float a = __expf(acc[mi][ni][r] - fmv[ni]) * fiv[ni];
        Ab[(size_t)q * L_ + ni * 16 + l15] = a;
        dsum[mi][r] += __expf(4.f * a);
      }
    }
#pragma unroll
  for (int mi = 0; mi < 4; mi++)
#pragma unroll
    for (int r = 0; r < 4; r++) {
      float v = dsum[mi][r];
      v += __shfl_xor(v, 1);
      v += __shfl_xor(v, 2);
      v += __shfl_xor(v, 4);
      v += __shfl_xor(v, 8);
      dsum[mi][r] = v;
    }
  if (l15 == 0) {
#pragma unroll
    for (int mi = 0; mi < 4; mi++)
#pragma unroll
      for (int r = 0; r < 4; r++)
        pd[(size_t)lt * (B_ * Q_) + b * Q_ + wq * 64 + mi * 16 + quad * 4 +
           r] = dsum[mi][r];
  }
}

__global__ __launch_bounds__(256) void k2_invd(const float* __restrict__ pd,
                                               float* __restrict__ invd) {
  const int i = blockIdx.x * 256 + threadIdx.x;
  float s = 0.f;
#pragma unroll
  for (int t = 0; t < 16; t++) s += pd[(size_t)t * (B_ * Q_) + i];
  invd[i] = 1.f / s;
}

__global__ __launch_bounds__(256) void k4_weighted(
    const float* __restrict__ ctx, float* __restrict__ attn,
    const float* __restrict__ invd, float* __restrict__ W) {
  __shared__ unsigned short As[128][32];
  __shared__ unsigned short Bs[64][32];
  const int b = blockIdx.y, q0 = blockIdx.x * 64;
  const int tid = threadIdx.x;
  const int w = tid >> 6, lane = tid & 63, quad = lane >> 4, l15 = lane & 15;
  const int wd = (w >> 1) * 64, wn = (w & 1) * 32;

  const float* Cb = ctx + (size_t)b * D_ * L_;
  float* Ab = attn + ((size_t)b * Q_ + q0) * L_;

  const int lc = (tid & 7) * 4;
  const int rr = tid >> 3;
  const float id0 = invd[b * Q_ + q0 + rr];
  const float id1 = invd[b * Q_ + q0 + rr + 32];

  f32x4 acc[4][2];
#pragma unroll
  for (int mi = 0; mi < 4; mi++)
#pragma unroll
    for (int ni = 0; ni < 2; ni++) acc[mi][ni] = (f32x4){0.f, 0.f, 0.f, 0.f};

  for (int l0 = 0; l0 < L_; l0 += 32) {
    if (l0) __syncthreads();
#pragma unroll
    for (int h = 0; h < 4; h++) {
      const int d = rr + h * 32;
      float4 cv = *(const float4*)(Cb + (size_t)d * L_ + l0 + lc);
      *(uint2*)&As[d][lc] = pack4bf(cv);
    }
#pragma unroll
    for (int h = 0; h < 2; h++) {
      const int q = rr + h * 32;
      float* p = Ab + (size_t)q * L_ + l0 + lc;
      float4 a = *(const float4*)p;
      const float idv = h ? id1 : id0;
      float4 t;
      t.x = __expf(4.f * a.x) * idv;
      t.y = __expf(4.f * a.y) * idv;
      t.z = __expf(4.f * a.z) * idv;
      t.w = __expf(4.f * a.w) * idv;
      *(float4*)p = t;
      *(uint2*)&Bs[q][lc] = pack4bf(t);
    }
    __syncthreads();

    s16x8 af[4], bq[2];
#pragma unroll
    for (int mi = 0; mi < 4; mi++)
      af[mi] = *(const s16x8*)&As[wd + mi * 16 + l15][quad * 8];
#pragma unroll
    for (int ni = 0; ni < 2; ni++)
      bq[ni] = *(const s16x8*)&Bs[wn + ni * 16 + l15][quad * 8];
#pragma unroll
    for (int mi = 0; mi < 4; mi++)
#pragma unroll
      for (int ni = 0; ni < 2; ni++)
        acc[mi][ni] = __builtin_amdgcn_mfma_f32_16x16x32_bf16(
            af[mi], bq[ni], acc[mi][ni], 0, 0, 0);
  }

  float* Wb = W + (size_t)b * D_ * Q_;
#pragma unroll
  for (int mi = 0; mi < 4; mi++)
#pragma unroll
    for (int ni = 0; ni < 2; ni++)
#pragma unroll
      for (int r = 0; r < 4; r++)
        Wb[(size_t)(wd + mi * 16 + quad * 4 + r) * Q_ + q0 + wn + ni * 16 +
           l15] = acc[mi][ni][r];
}

// ---------------------------------------------------------------------------
// d_out: [W (B*D*Q) | map (B*Q*L)]. Main path: R4 bodies (best: 300us) +
// XCD-locality swizzle (1-D grids; same-b blocks share an XCD so shared
// panels are L2-resident). attn_q never materialized. Fallback: legacy trio.
// ---------------------------------------------------------------------------
extern "C" void kernel_launch(void* const* d_in, const int* in_sizes, int n_in,
                              void* d_out, int out_size, void* d_ws,
                              size_t ws_size, hipStream_t stream) {
  (void)in_sizes;
  (void)n_in;
  (void)out_size;
  const float* query = (const float*)d_in[0];
  const float* ctx = (const float*)d_in[1];
  float* W = (float*)d_out;
  float* attn = (float*)d_out + (size_t)B_ * D_ * Q_;

  const size_t need =
      ((size_t)16 * B_ * Q_ + (size_t)2 * B_ * L_) * sizeof(float);
  if (d_ws && ws_size >= need) {
    float* pd = (float*)d_ws;
    float* fm = pd + (size_t)16 * B_ * Q_;
    float* fs = fm + (size_t)B_ * L_;
    k1_stats<<<dim3(L_ / 64 * B_), 256, 0, stream>>>(query, ctx, pd, fm, fs);
    k3_fused<<<dim3(Q_ / 64 * B_), 256, 0, stream>>>(query, ctx, pd, fm, fs,
                                                     attn, W);
  } else {
    const size_t need_pd = (size_t)17 * B_ * Q_ * sizeof(float);
    float* pd = (d_ws && ws_size >= need_pd) ? (float*)d_ws : W;
    float* invd = pd + (size_t)16 * B_ * Q_;
    k1_attnq_legacy<<<dim3(L_ / 64, B_), 256, 0, stream>>>(query, ctx, attn,
                                                           pd);
    k2_invd<<<dim3(B_ * Q_ / 256), 256, 0, stream>>>(pd, invd);
    k4_weighted<<<dim3(Q_ / 64, B_), 256, 0, stream>>>(ctx, attn, invd, W);
  }
}